// Round 13
// baseline (317.368 us; speedup 1.0000x reference)
//
#include <hip/hip_runtime.h>
#include <hip/hip_bf16.h>

#define N_ENT 50000
#define N_EDG 600000
#define CH 128
#define LEAKY 0.01f
#define NSTRIP 3125         // 50000 / 16
#define AGG_BLOCKS 6250     // 8 rows per block
#define FILL_CHUNK 4800     // 600000 = 125 * 4800
#define HEADS_PER_GRP 6250  // 50000 / 8
#define PREP_BLOCKS 6350    // 1,625,600 float4-units / 256
#define COUNT_BLOCKS 2344   // ceil(600000/256)
#define SCAN_C 49           // ceil(50000/1024)

typedef __attribute__((ext_vector_type(8))) short bf16x8;
typedef __attribute__((ext_vector_type(4))) float f32x4;

__device__ inline unsigned short f2bf(float x) {
    return __builtin_bit_cast(unsigned short, __float2bfloat16(x));
}
__device__ inline float bflo(unsigned u) { return __builtin_bit_cast(float, u << 16); }
__device__ inline float bfhi(unsigned u) { return __builtin_bit_cast(float, u & 0xFFFF0000u); }
__device__ inline int rfl(int x) { return __builtin_amdgcn_readfirstlane(x); }

// ---------------- prep: conversions + weight copy + degree counts ------------
__global__ __launch_bounds__(256) void prep_kernel(const float* __restrict__ emb,
                                                   const float* __restrict__ W1,
                                                   const float* __restrict__ W2,
                                                   const float* __restrict__ wsrc,
                                                   const int* __restrict__ head,
                                                   unsigned short* __restrict__ xh,
                                                   unsigned short* __restrict__ w1bf,
                                                   unsigned short* __restrict__ w2bf,
                                                   float* __restrict__ wout,
                                                   int* __restrict__ counts) {
    if (blockIdx.x >= PREP_BLOCKS) {
        int e = (blockIdx.x - PREP_BLOCKS) * 256 + threadIdx.x;
        if (e < N_EDG) atomicAdd(&counts[head[e]], 1);
        return;
    }
    long long gid = (long long)blockIdx.x * 256 + threadIdx.x;  // float4 units
    const long long n_x = (long long)N_ENT * CH / 4;   // 1,600,000
    const long long n_w1 = 2 * CH * CH / 4;            // 8,192
    const long long n_w2 = 2 * CH * 2 * CH / 4;        // 16,384
    if (gid < n_x) {
        long long k = gid * 4;
        float4 v = *(const float4*)&emb[k];
        ushort4 o;
        o.x = f2bf(v.x); o.y = f2bf(v.y); o.z = f2bf(v.z); o.w = f2bf(v.w);
        *(ushort4*)&xh[k] = o;
    } else if (gid < n_x + n_w1) {
        long long k = (gid - n_x) * 4;
        float4 v = *(const float4*)&W1[k];
        ushort4 o;
        o.x = f2bf(v.x); o.y = f2bf(v.y); o.z = f2bf(v.z); o.w = f2bf(v.w);
        *(ushort4*)&w1bf[k] = o;
    } else if (gid < n_x + n_w1 + n_w2) {
        long long k = (gid - n_x - n_w1) * 4;
        float4 v = *(const float4*)&W2[k];
        ushort4 o;
        o.x = f2bf(v.x); o.y = f2bf(v.y); o.z = f2bf(v.z); o.w = f2bf(v.w);
        *(ushort4*)&w2bf[k] = o;
    } else {
        long long k = (gid - n_x - n_w1 - n_w2) * 4;  // < 1024*4
        *(float4*)&wout[k] = *(const float4*)&wsrc[k];
    }
}

// ---------------- CSR scan: one workgroup, whole scan + cursor init ----------
__global__ __launch_bounds__(1024) void scan_kernel(const int* __restrict__ counts,
                                                    int* __restrict__ offs,
                                                    int* __restrict__ cursors) {
    __shared__ int s[1024];
    int t = threadIdx.x;
    int lo = t * SCAN_C;
    int hi = min(lo + SCAN_C, N_ENT);
    int sum = 0;
    for (int k = lo; k < hi; ++k) sum += counts[k];
    s[t] = sum;
    for (int off = 1; off < 1024; off <<= 1) {
        __syncthreads();
        int x = (t >= off) ? s[t - off] : 0;
        __syncthreads();
        s[t] += x;
    }
    __syncthreads();
    int run = s[t] - sum;  // exclusive prefix of this thread's chunk
    for (int k = lo; k < hi; ++k) {
        offs[k] = run;
        cursors[k] = run;
        run += counts[k];
    }
    if (t == 0) offs[N_ENT] = N_EDG;
}

// ---------------- CSR fill: packed edge payloads (XCD-partitioned) -----------
__global__ __launch_bounds__(256) void fill_kernel(const int* __restrict__ head,
                                                   const int* __restrict__ tail,
                                                   const int* __restrict__ etype,
                                                   int* __restrict__ cursors,
                                                   int* __restrict__ packed) {
    int g = blockIdx.x & 7;
    int c = blockIdx.x >> 3;  // 0..124
    int hlo = g * HEADS_PER_GRP;
    int hhi = hlo + HEADS_PER_GRP;
    int base = c * FILL_CHUNK;
    for (int t = threadIdx.x; t < FILL_CHUNK; t += 256) {
        int e = base + t;
        int h = head[e];
        if (h >= hlo && h < hhi) {
            int pos = atomicAdd(&cursors[h], 1);
            packed[pos] = tail[e] | (etype[e] << 20);
        }
    }
}

// ---------------- aggregate + mean + L2-normalize (quad-gather) --------------
// One wave per head row. Lane = (lq = edge slot 0..3, l16 = 16B chunk 0..15):
// ONE global_load_dwordx4 gathers 4 edges' rows (256B each) per issue; 2-quad
// unroll = 8 edges in flight. Tail edges masked via zero weight row 32.
// End: shfl_xor 16/32 reduces edge slots; mean+norm in-register; 16B store.
__global__ __launch_bounds__(512) void agg_kernel(
    const unsigned short* __restrict__ xin, const int* __restrict__ offs,
    const int* __restrict__ packed, const float* __restrict__ rw,
    unsigned short* __restrict__ aggb) {
    __shared__ float ws_[33 * CH];  // 32 rel-weight rows + zero row (16.5 KB)
    int tid = threadIdx.x;
    {
        int base = tid * 8;  // 4096 floats / 512 threads
        *(float4*)&ws_[base] = *(const float4*)&rw[base];
        *(float4*)&ws_[base + 4] = *(const float4*)&rw[base + 4];
        if (tid < 16) {
            f32x4 z = {0.f, 0.f, 0.f, 0.f};
            *(f32x4*)&ws_[32 * CH + tid * 8] = z;
            *(f32x4*)&ws_[32 * CH + tid * 8 + 4] = z;
        }
    }
    __syncthreads();

    const int w = tid >> 6;
    const int lane = tid & 63;
    const int l16 = lane & 15;
    const int lq = lane >> 4;
    const int c8 = l16 * 8;
    const int row = blockIdx.x * 8 + w;
    const int beg = rfl(offs[row]);
    const int end = rfl(offs[row + 1]);

    float a[8] = {0.f, 0.f, 0.f, 0.f, 0.f, 0.f, 0.f, 0.f};
    float b[8] = {0.f, 0.f, 0.f, 0.f, 0.f, 0.f, 0.f, 0.f};

    for (int i = beg; i < end; i += 8) {
        int pa0 = rfl(packed[i]);
        int pa1 = rfl(packed[i + 1]);
        int pa2 = rfl(packed[i + 2]);
        int pa3 = rfl(packed[i + 3]);
        int pb0 = rfl(packed[i + 4]);
        int pb1 = rfl(packed[i + 5]);
        int pb2 = rfl(packed[i + 6]);
        int pb3 = rfl(packed[i + 7]);
        int pA = lq == 0 ? pa0 : lq == 1 ? pa1 : lq == 2 ? pa2 : pa3;
        int pB = lq == 0 ? pb0 : lq == 1 ? pb1 : lq == 2 ? pb2 : pb3;
        bool okA = (i + lq) < end;
        bool okB = (i + 4 + lq) < end;
        int tA = (okA ? pA : pa0) & 0xFFFFF;
        int tB = (okB ? pB : pa0) & 0xFFFFF;
        int rA = okA ? (pA >> 20) : 32;
        int rB = okB ? (pB >> 20) : 32;
        uint4 vA = *(const uint4*)&xin[(long long)tA * CH + c8];
        uint4 vB = *(const uint4*)&xin[(long long)tB * CH + c8];
        float wvA[8], wvB[8];
        *(float4*)&wvA[0] = *(const float4*)&ws_[rA * CH + c8];
        *(float4*)&wvA[4] = *(const float4*)&ws_[rA * CH + c8 + 4];
        *(float4*)&wvB[0] = *(const float4*)&ws_[rB * CH + c8];
        *(float4*)&wvB[4] = *(const float4*)&ws_[rB * CH + c8 + 4];
        unsigned ua[4] = {vA.x, vA.y, vA.z, vA.w};
        unsigned ub[4] = {vB.x, vB.y, vB.z, vB.w};
#pragma unroll
        for (int k = 0; k < 4; ++k) {
            a[2 * k] = fmaf(bflo(ua[k]), wvA[2 * k], a[2 * k]);
            a[2 * k + 1] = fmaf(bfhi(ua[k]), wvA[2 * k + 1], a[2 * k + 1]);
            b[2 * k] = fmaf(bflo(ub[k]), wvB[2 * k], b[2 * k]);
            b[2 * k + 1] = fmaf(bfhi(ub[k]), wvB[2 * k + 1], b[2 * k + 1]);
        }
    }

#pragma unroll
    for (int k = 0; k < 8; ++k) {
        a[k] += b[k];
        a[k] += __shfl_xor(a[k], 16);
        a[k] += __shfl_xor(a[k], 32);
    }
    float dinv = 1.0f / fmaxf((float)(end - beg), 1.f);
    float ss = 0.f;
#pragma unroll
    for (int k = 0; k < 8; ++k) {
        a[k] *= dinv;
        ss = fmaf(a[k], a[k], ss);
    }
#pragma unroll
    for (int off = 1; off <= 8; off <<= 1) ss += __shfl_xor(ss, off);
    float inv = 1.0f / fmaxf(sqrtf(ss), 1e-12f);
    if (lq == 0) {
        unsigned o0 = (unsigned)f2bf(a[0] * inv) | ((unsigned)f2bf(a[1] * inv) << 16);
        unsigned o1 = (unsigned)f2bf(a[2] * inv) | ((unsigned)f2bf(a[3] * inv) << 16);
        unsigned o2 = (unsigned)f2bf(a[4] * inv) | ((unsigned)f2bf(a[5] * inv) << 16);
        unsigned o3 = (unsigned)f2bf(a[6] * inv) | ((unsigned)f2bf(a[7] * inv) << 16);
        uint4 ov = {o0, o1, o2, o3};
        *(uint4*)&aggb[(long long)row * CH + c8] = ov;
    }
}

// ---------------- MFMA dual-GEMM + leaky + add (r11 verbatim) ----------------
__global__ __launch_bounds__(512) void gemm_kernel(
    const unsigned short* __restrict__ xin, const unsigned short* __restrict__ aggb,
    const unsigned short* __restrict__ w1bf, const unsigned short* __restrict__ w2bf,
    const float* __restrict__ b1, const float* __restrict__ b2,
    unsigned short* __restrict__ xout, float* __restrict__ outf) {
    __shared__ __align__(16) unsigned char lds[8192];  // [2][16 rows][256 B]

    const int tid = threadIdx.x;
    const int w = tid >> 6;
    const int lane = tid & 63;
    const int l16 = lane & 15;
    const int lq = lane >> 4;
    const int j = w * 16 + l16;
    const int row0 = blockIdx.x * 16;

    {
        int half = w >> 2;
        int r = (w & 3) * 4 + lq;
        int c = l16;
        const unsigned short* src = half ? aggb : xin;
        bf16x8 v = *(const bf16x8*)&src[(long long)(row0 + r) * CH + c * 8];
        *(bf16x8*)&lds[half * 4096 + r * 256 + ((c ^ r) * 16)] = v;
    }

    bf16x8 bW1[4], bWa[4], bWb[4];
    const float bb1 = b1[j];
    const float bb2 = b2[j];
#pragma unroll
    for (int kst = 0; kst < 4; ++kst) {
        int kk = kst * 32 + lq * 8;
        bW1[kst] = *(const bf16x8*)&w1bf[j * CH + kk];
        bWa[kst] = *(const bf16x8*)&w2bf[j * 2 * CH + kk];
        bWb[kst] = *(const bf16x8*)&w2bf[j * 2 * CH + CH + kk];
    }
    __syncthreads();

    f32x4 acc1 = {0.f, 0.f, 0.f, 0.f};
    f32x4 acc2 = {0.f, 0.f, 0.f, 0.f};
#pragma unroll
    for (int kst = 0; kst < 4; ++kst) {
        int c = kst * 4 + lq;
        int off = l16 * 256 + ((c ^ l16) * 16);
        bf16x8 rh = *(const bf16x8*)&lds[off];
        bf16x8 av = *(const bf16x8*)&lds[4096 + off];
        acc1 = __builtin_amdgcn_mfma_f32_16x16x32_bf16(rh, bW1[kst], acc1, 0, 0, 0);
        acc1 = __builtin_amdgcn_mfma_f32_16x16x32_bf16(av, bW1[kst], acc1, 0, 0, 0);
        acc2 = __builtin_amdgcn_mfma_f32_16x16x32_bf16(rh, bWa[kst], acc2, 0, 0, 0);
        acc2 = __builtin_amdgcn_mfma_f32_16x16x32_bf16(av, bWb[kst], acc2, 0, 0, 0);
    }

#pragma unroll
    for (int r = 0; r < 4; ++r) {
        long long row = row0 + lq * 4 + r;
        float e1 = acc1[r] + bb1;
        e1 = e1 >= 0.f ? e1 : LEAKY * e1;
        float e2 = acc2[r] + bb2;
        e2 = e2 >= 0.f ? e2 : LEAKY * e2;
        float val = e1 + e2;
        if (outf)
            outf[row * CH + j] = val;
        else
            xout[row * CH + j] = f2bf(val);
    }
}

extern "C" void kernel_launch(void* const* d_in, const int* in_sizes, int n_in,
                              void* d_out, int out_size, void* d_ws, size_t ws_size,
                              hipStream_t stream) {
    const float* emb = (const float*)d_in[0];
    const int* eidx = (const int*)d_in[1];   // int inputs arrive as int32
    const int* etype = (const int*)d_in[2];
    const float* weight = (const float*)d_in[3];
    const float* W1w = (const float*)d_in[4];
    const float* W1b = (const float*)d_in[5];
    const float* W2w = (const float*)d_in[6];
    const float* W2b = (const float*)d_in[7];

    float* out = (float*)d_out;
    float* wout = out + (size_t)N_ENT * CH;   // [32][CH]

    // workspace layout (~41.6 MB; proven fits)
    char* ws = (char*)d_ws;
    unsigned short* xh = (unsigned short*)ws;    ws += (size_t)N_ENT * CH * 2;  // 12.8 MB
    unsigned short* xh2 = (unsigned short*)ws;   ws += (size_t)N_ENT * CH * 2;  // 12.8 MB
    unsigned short* aggb = (unsigned short*)ws;  ws += (size_t)N_ENT * CH * 2;  // 12.8 MB
    unsigned short* w1bf = (unsigned short*)ws;  ws += 2 * CH * CH * 2;         // 64 KB
    unsigned short* w2bf = (unsigned short*)ws;  ws += 2 * CH * 2 * CH * 2;     // 128 KB
    int* packed = (int*)ws;                      ws += (size_t)(N_EDG + 8) * 4; // 2.4 MB (+quad slack)
    int* offs = (int*)ws;                        ws += (size_t)(N_ENT + 1) * 4;
    int* cursors = (int*)ws;                     ws += (size_t)N_ENT * 4;
    int* counts = (int*)ws;                      ws += (size_t)N_ENT * 4;

    const int* head = eidx;
    const int* tail = eidx + N_EDG;

    // ---- one-time prep: counts+conversions fused, single-WG scan, fill ----
    hipMemsetAsync(counts, 0, N_ENT * sizeof(int), stream);
    prep_kernel<<<PREP_BLOCKS + COUNT_BLOCKS, 256, 0, stream>>>(
        emb, W1w, W2w, weight, head, xh, w1bf, w2bf, wout, counts);
    scan_kernel<<<1, 1024, 0, stream>>>(counts, offs, cursors);
    fill_kernel<<<1000, 256, 0, stream>>>(head, tail, etype, cursors, packed);

    // ---- 2 hops, ping-pong: xh -> (aggb) -> xh2 -> (aggb) -> d_out ----
    agg_kernel<<<AGG_BLOCKS, 512, 0, stream>>>(xh, offs, packed, weight, aggb);
    gemm_kernel<<<NSTRIP, 512, 0, stream>>>(
        xh, aggb, w1bf, w2bf, W1b, W2b, xh2, (float*)nullptr);
    agg_kernel<<<AGG_BLOCKS, 512, 0, stream>>>(xh2, offs, packed, weight, aggb);
    gemm_kernel<<<NSTRIP, 512, 0, stream>>>(
        xh2, aggb, w1bf + CH * CH, w2bf + CH * 2 * CH,
        W1b + CH, W2b + CH, (unsigned short*)nullptr, out);
}

// Round 14
// 197.379 us; speedup vs baseline: 1.6079x; 1.6079x over previous
//
#include <hip/hip_runtime.h>
#include <hip/hip_bf16.h>

#define N_ENT 50000
#define N_EDG 600000
#define CH 128
#define LEAKY 0.01f
#define NB_SCAN 49
#define NSTRIP 3125         // 50000 / 16
#define AGG_BLOCKS 1024     // grid-stride over 6250 row-groups of 8
#define GEMM_BLOCKS 256     // 16 waves each, 2 strip-streams, stride 512
#define FILL_CHUNK 4800     // 600000 = 125 * 4800
#define HEADS_PER_GRP 6250  // 50000 / 8
#define PREP_BLOCKS 6351    // ceil(1,625,632 float4-units / 256)
#define COUNT_BLOCKS 2344   // ceil(600000/256)

typedef __attribute__((ext_vector_type(8))) short bf16x8;
typedef __attribute__((ext_vector_type(4))) float f32x4;

__device__ inline unsigned short f2bf(float x) {
    return __builtin_bit_cast(unsigned short, __float2bfloat16(x));
}
__device__ inline float bflo(unsigned u) { return __builtin_bit_cast(float, u << 16); }
__device__ inline float bfhi(unsigned u) { return __builtin_bit_cast(float, u & 0xFFFF0000u); }
__device__ inline int rfl(int x) { return __builtin_amdgcn_readfirstlane(x); }

// ---------------- prep: conversions + weight copies + degree counts ----------
__global__ __launch_bounds__(256) void prep_kernel(const float* __restrict__ emb,
                                                   const float* __restrict__ W1,
                                                   const float* __restrict__ W2,
                                                   const float* __restrict__ wsrc,
                                                   const int* __restrict__ head,
                                                   unsigned short* __restrict__ xh,
                                                   unsigned short* __restrict__ w1bf,
                                                   unsigned short* __restrict__ w2bf,
                                                   float* __restrict__ wout,
                                                   float* __restrict__ wsf,
                                                   int* __restrict__ counts) {
    if (blockIdx.x >= PREP_BLOCKS) {
        int e = (blockIdx.x - PREP_BLOCKS) * 256 + threadIdx.x;
        if (e < N_EDG) atomicAdd(&counts[head[e]], 1);
        return;
    }
    long long gid = (long long)blockIdx.x * 256 + threadIdx.x;  // float4 units
    const long long n_x = (long long)N_ENT * CH / 4;   // 1,600,000
    const long long n_w1 = 2 * CH * CH / 4;            // 8,192
    const long long n_w2 = 2 * CH * 2 * CH / 4;        // 16,384
    if (gid < n_x) {
        long long k = gid * 4;
        float4 v = *(const float4*)&emb[k];
        ushort4 o;
        o.x = f2bf(v.x); o.y = f2bf(v.y); o.z = f2bf(v.z); o.w = f2bf(v.w);
        *(ushort4*)&xh[k] = o;
    } else if (gid < n_x + n_w1) {
        long long k = (gid - n_x) * 4;
        float4 v = *(const float4*)&W1[k];
        ushort4 o;
        o.x = f2bf(v.x); o.y = f2bf(v.y); o.z = f2bf(v.z); o.w = f2bf(v.w);
        *(ushort4*)&w1bf[k] = o;
    } else if (gid < n_x + n_w1 + n_w2) {
        long long k = (gid - n_x - n_w1) * 4;
        float4 v = *(const float4*)&W2[k];
        ushort4 o;
        o.x = f2bf(v.x); o.y = f2bf(v.y); o.z = f2bf(v.z); o.w = f2bf(v.w);
        *(ushort4*)&w2bf[k] = o;
    } else {
        long long k = gid - n_x - n_w1 - n_w2;  // float4 units
        if (k < 1024) {
            float4 v = *(const float4*)&wsrc[k * 4];
            *(float4*)&wout[k * 4] = v;
            *(float4*)&wsf[k * 4] = v;
        } else if (k < 1056) {  // zero row 32 of wsf (tail-edge masking)
            float4 z = {0.f, 0.f, 0.f, 0.f};
            *(float4*)&wsf[k * 4] = z;
        }
    }
}

// ---------------- CSR step 2a: per-1024-chunk exclusive scan ----------------
__global__ __launch_bounds__(256) void scan_block(const int* __restrict__ counts,
                                                  int* __restrict__ offs,
                                                  int* __restrict__ bsum) {
    __shared__ int s[256];
    int t = threadIdx.x;
    int base = blockIdx.x * 1024 + t * 4;
    int v[4];
#pragma unroll
    for (int i = 0; i < 4; ++i) {
        int idx = base + i;
        v[i] = (idx < N_ENT) ? counts[idx] : 0;
    }
    int tot = v[0] + v[1] + v[2] + v[3];
    s[t] = tot;
    for (int off = 1; off < 256; off <<= 1) {
        __syncthreads();
        int x = (t >= off) ? s[t - off] : 0;
        __syncthreads();
        s[t] += x;
    }
    int run = s[t] - tot;
#pragma unroll
    for (int i = 0; i < 4; ++i) {
        if (base + i < N_ENT) offs[base + i] = run;
        run += v[i];
    }
    if (t == 255) bsum[blockIdx.x] = s[255];
}

// ---------------- CSR step 2b: scan the 49 chunk totals ----------------------
__global__ __launch_bounds__(64) void scan_tops(int* __restrict__ bsum) {
    int lane = threadIdx.x;
    int v = (lane < NB_SCAN) ? bsum[lane] : 0;
    int orig = v;
#pragma unroll
    for (int off = 1; off < 64; off <<= 1) {
        int x = __shfl_up(v, off);
        if (lane >= off) v += x;
    }
    if (lane < NB_SCAN) bsum[lane] = v - orig;
}

// ---------------- CSR step 2c: add chunk base, init cursors ------------------
__global__ __launch_bounds__(256) void add_base(int* __restrict__ offs,
                                                int* __restrict__ cursors,
                                                const int* __restrict__ bsum) {
    int t = threadIdx.x;
    int base = blockIdx.x * 1024 + t * 4;
    int b = bsum[blockIdx.x];
#pragma unroll
    for (int i = 0; i < 4; ++i) {
        int idx = base + i;
        if (idx < N_ENT) {
            int o = offs[idx] + b;
            offs[idx] = o;
            cursors[idx] = o;
        }
    }
    if (blockIdx.x == 0 && t == 0) offs[N_ENT] = N_EDG;
}

// ---------------- CSR fill: packed edge payloads (XCD-partitioned) -----------
__global__ __launch_bounds__(256) void fill_kernel(const int* __restrict__ head,
                                                   const int* __restrict__ tail,
                                                   const int* __restrict__ etype,
                                                   int* __restrict__ cursors,
                                                   int* __restrict__ packed) {
    int g = blockIdx.x & 7;
    int c = blockIdx.x >> 3;  // 0..124
    int hlo = g * HEADS_PER_GRP;
    int hhi = hlo + HEADS_PER_GRP;
    int base = c * FILL_CHUNK;
    for (int t = threadIdx.x; t < FILL_CHUNK; t += 256) {
        int e = base + t;
        int h = head[e];
        if (h >= hlo && h < hhi) {
            int pos = atomicAdd(&cursors[h], 1);
            packed[pos] = tail[e] | (etype[e] << 20);
        }
    }
}

// ---------------- aggregate + mean + L2-normalize (quad-gather, amortized) ---
// 1024 blocks grid-stride over 6250 row-groups: LDS weight staging paid 1024x
// instead of 6250x. One wave per row; lane = (lq = edge slot, l16 = 16B chunk);
// one dwordx4 gathers 4 edges' rows; 2-quad unroll = 8 edges in flight.
// Tail edges masked via zero weight row 32. LDS stride 132 = bank-spread.
__global__ __launch_bounds__(512) void agg_kernel(
    const unsigned short* __restrict__ xin, const int* __restrict__ offs,
    const int* __restrict__ packed, const float* __restrict__ wsf,
    unsigned short* __restrict__ aggb) {
    __shared__ float ws_[33 * 132];  // 17.4 KB
    int tid = threadIdx.x;
    for (int q = tid; q < 1056; q += 512) {  // 33 rows x 32 float4
        float4 v = *(const float4*)&wsf[q * 4];
        *(float4*)&ws_[(q >> 5) * 132 + (q & 31) * 4] = v;
    }
    __syncthreads();

    const int w = tid >> 6;
    const int lane = tid & 63;
    const int l16 = lane & 15;
    const int lq = lane >> 4;
    const int c8 = l16 * 8;

    for (int rb = blockIdx.x; rb < 6250; rb += AGG_BLOCKS) {
        const int row = rb * 8 + w;
        const int beg = rfl(offs[row]);
        const int end = rfl(offs[row + 1]);

        float a[8] = {0.f, 0.f, 0.f, 0.f, 0.f, 0.f, 0.f, 0.f};
        float b[8] = {0.f, 0.f, 0.f, 0.f, 0.f, 0.f, 0.f, 0.f};

        for (int i = beg; i < end; i += 8) {
            int pa0 = rfl(packed[i]);
            int pa1 = rfl(packed[i + 1]);
            int pa2 = rfl(packed[i + 2]);
            int pa3 = rfl(packed[i + 3]);
            int pb0 = rfl(packed[i + 4]);
            int pb1 = rfl(packed[i + 5]);
            int pb2 = rfl(packed[i + 6]);
            int pb3 = rfl(packed[i + 7]);
            int pA = lq == 0 ? pa0 : lq == 1 ? pa1 : lq == 2 ? pa2 : pa3;
            int pB = lq == 0 ? pb0 : lq == 1 ? pb1 : lq == 2 ? pb2 : pb3;
            bool okA = (i + lq) < end;
            bool okB = (i + 4 + lq) < end;
            int tA = (okA ? pA : pa0) & 0xFFFFF;
            int tB = (okB ? pB : pa0) & 0xFFFFF;
            int rA = okA ? (pA >> 20) : 32;
            int rB = okB ? (pB >> 20) : 32;
            uint4 vA = *(const uint4*)&xin[(long long)tA * CH + c8];
            uint4 vB = *(const uint4*)&xin[(long long)tB * CH + c8];
            float wvA[8], wvB[8];
            *(float4*)&wvA[0] = *(const float4*)&ws_[rA * 132 + c8];
            *(float4*)&wvA[4] = *(const float4*)&ws_[rA * 132 + c8 + 4];
            *(float4*)&wvB[0] = *(const float4*)&ws_[rB * 132 + c8];
            *(float4*)&wvB[4] = *(const float4*)&ws_[rB * 132 + c8 + 4];
            unsigned ua[4] = {vA.x, vA.y, vA.z, vA.w};
            unsigned ub[4] = {vB.x, vB.y, vB.z, vB.w};
#pragma unroll
            for (int k = 0; k < 4; ++k) {
                a[2 * k] = fmaf(bflo(ua[k]), wvA[2 * k], a[2 * k]);
                a[2 * k + 1] = fmaf(bfhi(ua[k]), wvA[2 * k + 1], a[2 * k + 1]);
                b[2 * k] = fmaf(bflo(ub[k]), wvB[2 * k], b[2 * k]);
                b[2 * k + 1] = fmaf(bfhi(ub[k]), wvB[2 * k + 1], b[2 * k + 1]);
            }
        }

#pragma unroll
        for (int k = 0; k < 8; ++k) {
            a[k] += b[k];
            a[k] += __shfl_xor(a[k], 16);
            a[k] += __shfl_xor(a[k], 32);
        }
        float dinv = 1.0f / fmaxf((float)(end - beg), 1.f);
        float ss = 0.f;
#pragma unroll
        for (int k = 0; k < 8; ++k) {
            a[k] *= dinv;
            ss = fmaf(a[k], a[k], ss);
        }
#pragma unroll
        for (int off = 1; off <= 8; off <<= 1) ss += __shfl_xor(ss, off);
        float inv = 1.0f / fmaxf(sqrtf(ss), 1e-12f);
        if (lq == 0) {
            unsigned o0 = (unsigned)f2bf(a[0] * inv) | ((unsigned)f2bf(a[1] * inv) << 16);
            unsigned o1 = (unsigned)f2bf(a[2] * inv) | ((unsigned)f2bf(a[3] * inv) << 16);
            unsigned o2 = (unsigned)f2bf(a[4] * inv) | ((unsigned)f2bf(a[5] * inv) << 16);
            unsigned o3 = (unsigned)f2bf(a[6] * inv) | ((unsigned)f2bf(a[7] * inv) << 16);
            uint4 ov = {o0, o1, o2, o3};
            *(uint4*)&aggb[(long long)row * CH + c8] = ov;
        }
    }
}

// ---------------- MFMA dual-GEMM + leaky + add (weights LDS-resident) --------
// 256 blocks x 1024 threads. ALL weights (96KB) staged to LDS once per block
// (XOR-swizzled, 2-way max conflict) -> weight traffic 300MB -> 24MB. 16 waves
// = 2 independent strip streams (h = w>>3), no barriers in the loop. A read
// per-lane from global; B-frags from LDS (remat-safe: remat = cheap ds_read).
__global__ __launch_bounds__(1024) void gemm_kernel(
    const unsigned short* __restrict__ xin, const unsigned short* __restrict__ aggb,
    const unsigned short* __restrict__ w1bf, const unsigned short* __restrict__ w2bf,
    const float* __restrict__ b1, const float* __restrict__ b2,
    unsigned short* __restrict__ xout, float* __restrict__ outf) {
    __shared__ __align__(16) unsigned short w1s[CH * CH];      // 32 KB
    __shared__ __align__(16) unsigned short w2s[CH * 2 * CH];  // 64 KB

    const int tid = threadIdx.x;
    // stage weights: 6144 16B-chunks over 1024 threads, swizzle chunk^(row&7)
    for (int q = tid; q < 6144; q += 1024) {
        if (q < 2048) {
            int j = q >> 4, c = q & 15;
            *(bf16x8*)&w1s[j * CH + ((c ^ (j & 7)) << 3)] =
                *(const bf16x8*)&w1bf[j * CH + c * 8];
        } else {
            int qq = q - 2048;
            int j = qq >> 5, c = qq & 31;
            *(bf16x8*)&w2s[j * 2 * CH + ((c ^ (j & 7)) << 3)] =
                *(const bf16x8*)&w2bf[j * 2 * CH + c * 8];
        }
    }
    __syncthreads();

    const int w = tid >> 6;
    const int h = w >> 3;   // strip stream 0/1
    const int wc = w & 7;   // col group
    const int lane = tid & 63;
    const int l16 = lane & 15;
    const int lq = lane >> 4;
    const int j = wc * 16 + l16;
    const float bb1 = b1[j];
    const float bb2 = b2[j];

    bf16x8 bW1[4], bWa[4], bWb[4];
#pragma unroll
    for (int kst = 0; kst < 4; ++kst) {
        int ca = kst * 4 + lq;
        int cb = 16 + kst * 4 + lq;
        bW1[kst] = *(const bf16x8*)&w1s[j * CH + ((ca ^ (j & 7)) << 3)];
        bWa[kst] = *(const bf16x8*)&w2s[j * 2 * CH + ((ca ^ (j & 7)) << 3)];
        bWb[kst] = *(const bf16x8*)&w2s[j * 2 * CH + ((cb ^ (j & 7)) << 3)];
    }

    for (int s = blockIdx.x * 2 + h; s < NSTRIP; s += 2 * GEMM_BLOCKS) {
        const int row0 = s * 16;
        long long abase = (long long)(row0 + l16) * CH + lq * 8;
        f32x4 acc1 = {0.f, 0.f, 0.f, 0.f};
        f32x4 acc2 = {0.f, 0.f, 0.f, 0.f};
#pragma unroll
        for (int kst = 0; kst < 4; ++kst) {
            bf16x8 rh = *(const bf16x8*)&xin[abase + kst * 32];
            bf16x8 av = *(const bf16x8*)&aggb[abase + kst * 32];
            acc1 = __builtin_amdgcn_mfma_f32_16x16x32_bf16(rh, bW1[kst], acc1, 0, 0, 0);
            acc1 = __builtin_amdgcn_mfma_f32_16x16x32_bf16(av, bW1[kst], acc1, 0, 0, 0);
            acc2 = __builtin_amdgcn_mfma_f32_16x16x32_bf16(rh, bWa[kst], acc2, 0, 0, 0);
            acc2 = __builtin_amdgcn_mfma_f32_16x16x32_bf16(av, bWb[kst], acc2, 0, 0, 0);
        }
#pragma unroll
        for (int r = 0; r < 4; ++r) {
            long long row = row0 + lq * 4 + r;
            float e1 = acc1[r] + bb1;
            e1 = e1 >= 0.f ? e1 : LEAKY * e1;
            float e2 = acc2[r] + bb2;
            e2 = e2 >= 0.f ? e2 : LEAKY * e2;
            float val = e1 + e2;
            if (outf)
                outf[row * CH + j] = val;
            else
                xout[row * CH + j] = f2bf(val);
        }
    }
}

extern "C" void kernel_launch(void* const* d_in, const int* in_sizes, int n_in,
                              void* d_out, int out_size, void* d_ws, size_t ws_size,
                              hipStream_t stream) {
    const float* emb = (const float*)d_in[0];
    const int* eidx = (const int*)d_in[1];   // int inputs arrive as int32
    const int* etype = (const int*)d_in[2];
    const float* weight = (const float*)d_in[3];
    const float* W1w = (const float*)d_in[4];
    const float* W1b = (const float*)d_in[5];
    const float* W2w = (const float*)d_in[6];
    const float* W2b = (const float*)d_in[7];

    float* out = (float*)d_out;
    float* wout = out + (size_t)N_ENT * CH;   // [32][CH]

    // workspace layout (~41.7 MB; proven fits)
    char* ws = (char*)d_ws;
    unsigned short* xh = (unsigned short*)ws;    ws += (size_t)N_ENT * CH * 2;  // 12.8 MB
    unsigned short* xh2 = (unsigned short*)ws;   ws += (size_t)N_ENT * CH * 2;  // 12.8 MB
    unsigned short* aggb = (unsigned short*)ws;  ws += (size_t)N_ENT * CH * 2;  // 12.8 MB
    unsigned short* w1bf = (unsigned short*)ws;  ws += 2 * CH * CH * 2;         // 64 KB
    unsigned short* w2bf = (unsigned short*)ws;  ws += 2 * CH * 2 * CH * 2;     // 128 KB
    float* wsf = (float*)ws;                     ws += 33 * CH * 4;             // 16.9 KB
    int* packed = (int*)ws;                      ws += (size_t)(N_EDG + 8) * 4; // 2.4 MB
    int* offs = (int*)ws;                        ws += (size_t)(N_ENT + 1) * 4;
    int* cursors = (int*)ws;                     ws += (size_t)N_ENT * 4;
    int* counts = (int*)ws;                      ws += (size_t)N_ENT * 4;
    int* bsum = (int*)ws;                        ws += 64 * 4;

    const int* head = eidx;
    const int* tail = eidx + N_EDG;

    // ---- one-time prep: counts+conversions fused, 3-kernel scan, fill ----
    hipMemsetAsync(counts, 0, N_ENT * sizeof(int), stream);
    prep_kernel<<<PREP_BLOCKS + COUNT_BLOCKS, 256, 0, stream>>>(
        emb, W1w, W2w, weight, head, xh, w1bf, w2bf, wout, wsf, counts);
    scan_block<<<NB_SCAN, 256, 0, stream>>>(counts, offs, bsum);
    scan_tops<<<1, 64, 0, stream>>>(bsum);
    add_base<<<NB_SCAN, 256, 0, stream>>>(offs, cursors, bsum);
    fill_kernel<<<1000, 256, 0, stream>>>(head, tail, etype, cursors, packed);

    // ---- 2 hops, ping-pong: xh -> (aggb) -> xh2 -> (aggb) -> d_out ----
    agg_kernel<<<AGG_BLOCKS, 512, 0, stream>>>(xh, offs, packed, wsf, aggb);
    gemm_kernel<<<GEMM_BLOCKS, 1024, 0, stream>>>(
        xh, aggb, w1bf, w2bf, W1b, W2b, xh2, (float*)nullptr);
    agg_kernel<<<AGG_BLOCKS, 512, 0, stream>>>(xh2, offs, packed, wsf, aggb);
    gemm_kernel<<<GEMM_BLOCKS, 1024, 0, stream>>>(
        xh2, aggb, w1bf + CH * CH, w2bf + CH * 2 * CH,
        W1b + CH, W2b + CH, (unsigned short*)nullptr, out);
}